// Round 3
// baseline (458.267 us; speedup 1.0000x reference)
//
#include <hip/hip_runtime.h>
#include <stdint.h>

#define BATCH   16
#define NANCH   25200
#define NCLS    80
#define REC     85
#define MAXDET  300
#define TMAX    50
#define CAP     8192
#define NBUCKET 2048
#define FINCAP  1024

// output offsets (floats)
#define OFF_PB 0
#define OFF_PS 19200
#define OFF_PL 24000
#define OFF_PK 28800
#define OFF_TB 33600
#define OFF_TS 36800
#define OFF_TL 37600
#define OFF_TV 38400

__device__ __forceinline__ float opaque_f(float x) { asm volatile("" : "+v"(x)); return x; }

// ---------------- Kernel A: score + compact candidates ----------------
// Wave-per-anchor: lane l loads rec[l] (256B contiguous) and rec[64+l] (l<21).
// Every wave VMEM instruction touches 1-2 cache lines, fully consumed ->
// coalesced, miss-queue friendly. 8 anchors per wave, loads issued up front.
__global__ __launch_bounds__(256) void kA(const float* __restrict__ logits,
                                          int* __restrict__ cnt,
                                          unsigned long long* __restrict__ keys) {
    const int wid  = (blockIdx.x * 256 + threadIdx.x) >> 6;   // global wave id
    const int lane = threadIdx.x & 63;
    const int a0   = wid * 8;                                 // 403200/8 waves exact
    const float* base = logits + (size_t)a0 * REC;
    float va[8], vb[8];
#pragma unroll
    for (int k = 0; k < 8; ++k) {
        const float* rec = base + k * REC;
        va[k] = rec[lane];                                    // fields 0..63
        vb[k] = (lane < 21) ? rec[64 + lane] : -1.0f;         // fields 64..84
    }
#pragma unroll
    for (int k = 0; k < 8; ++k) {
        // classes are fields 5..84 -> va lanes 5..63, vb lanes 0..20
        float m = fmaxf((lane >= 5) ? va[k] : -1.0f, vb[k]);  // values in [0,1)
        m = fmaxf(m, __shfl_xor(m, 32));
        m = fmaxf(m, __shfl_xor(m, 16));
        m = fmaxf(m, __shfl_xor(m, 8));
        m = fmaxf(m, __shfl_xor(m, 4));
        m = fmaxf(m, __shfl_xor(m, 2));
        m = fmaxf(m, __shfl_xor(m, 1));
        float obj  = __shfl(va[k], 4);                        // field 4
        float conf = obj * m;                                 // exact: single multiply
        if (lane == 0 && conf > 0.8f) {
            int g = a0 + k;
            int b = g / NANCH;
            int n = g - b * NANCH;
            int pos = atomicAdd(cnt + b * 16, 1);             // counters padded 64B
            if (pos < CAP) {
                unsigned long long key =
                    ((unsigned long long)__float_as_uint(conf) << 32) |
                    (unsigned)(0xFFFFFFFFu - (unsigned)n);    // ties: smaller idx first
                keys[(size_t)b * CAP + pos] = key;
            }
        }
    }
}

// ---------------- Kernel B: radix-select + bitonic top-300 ----------------
__global__ __launch_bounds__(1024) void kB(const int* __restrict__ cnt,
                                           const unsigned long long* __restrict__ keys,
                                           unsigned long long* __restrict__ topkeys) {
    __shared__ unsigned hist[NBUCKET];
    __shared__ unsigned long long fin[FINCAP];
    __shared__ int sTb, sCnt;
    const int b = blockIdx.x;
    const int tid = threadIdx.x;
    int cb = cnt[b * 16]; if (cb > CAP) cb = CAP;
    const unsigned long long* kb = keys + (size_t)b * CAP;

    for (int i = tid; i < NBUCKET; i += 1024) hist[i] = 0u;
    if (tid == 0) sCnt = 0;
    __syncthreads();
    for (int i = tid; i < cb; i += 1024) {
        unsigned bits = (unsigned)(kb[i] >> 32);      // conf bits, > 0x3F4CCCCD
        unsigned bk = (bits - 0x3F4CCCCDu) >> 11;     // linear in value (one binade)
        if (bk > NBUCKET - 1u) bk = NBUCKET - 1u;
        atomicAdd(&hist[bk], 1u);
    }
    __syncthreads();
    if (tid == 0) {
        int c = 0, tb = 0;
        for (int bk = NBUCKET - 1; bk >= 0; --bk) {
            c += (int)hist[bk];
            if (c >= MAXDET) { tb = bk; break; }
        }
        sTb = tb;
    }
    __syncthreads();
    int tb = sTb;
    for (int i = tid; i < cb; i += 1024) {
        unsigned long long k = kb[i];
        unsigned bits = (unsigned)(k >> 32);
        unsigned bk = (bits - 0x3F4CCCCDu) >> 11;
        if (bk > NBUCKET - 1u) bk = NBUCKET - 1u;
        if ((int)bk >= tb) {
            int p = atomicAdd(&sCnt, 1);
            if (p < FINCAP) fin[p] = k;
        }
    }
    __syncthreads();
    int fc = sCnt; if (fc > FINCAP) fc = FINCAP;
    for (int i = tid; i < FINCAP; i += 1024) if (i >= fc) fin[i] = 0ull;
    // bitonic sort descending (keys unique -> deterministic)
    for (unsigned k = 2; k <= FINCAP; k <<= 1) {
        for (unsigned j = k >> 1; j > 0; j >>= 1) {
            __syncthreads();
            unsigned t = tid;
            unsigned ixj = t ^ j;
            if (ixj > t && t < FINCAP) {
                unsigned long long a = fin[t], c2 = fin[ixj];
                bool desc = ((t & k) == 0u);
                bool sw = desc ? (a < c2) : (a > c2);
                if (sw) { fin[t] = c2; fin[ixj] = a; }
            }
        }
    }
    __syncthreads();
    if (tid < MAXDET) topkeys[b * MAXDET + tid] = fin[tid];
}

// ---------------- Kernel C: gather + NMS + outputs ----------------
__global__ __launch_bounds__(512) void kC(const float* __restrict__ logits,
                                          const unsigned long long* __restrict__ topkeys,
                                          float* __restrict__ out) {
    __shared__ float bx1[MAXDET], by1[MAXDET], bx2[MAXDET], by2[MAXDET];
    __shared__ unsigned supp[MAXDET * 10];   // 300 rows x 320 bits
    __shared__ unsigned keepw[10];
    const int b = blockIdx.x;
    const int tid = threadIdx.x;
    for (int i = tid; i < MAXDET * 10; i += 512) supp[i] = 0u;
    if (tid < MAXDET) {
        unsigned long long key = topkeys[b * MAXDET + tid];
        float score = __uint_as_float((unsigned)(key >> 32));
        unsigned n = 0xFFFFFFFFu - (unsigned)(key & 0xFFFFFFFFull);
        if (n >= NANCH) n = 0;     // safety only; count >= 300 always
        const float* rec = logits + ((size_t)b * NANCH + n) * REC;
        float cx = rec[0], cy = rec[1], w = rec[2], h = rec[3];
        float bestv = rec[5]; int lab = 0;
        for (int c = 1; c < NCLS; ++c) {
            float v = rec[5 + c];
            if (v > bestv) { bestv = v; lab = c; }   // first-max, matches argmax
        }
        float hw = opaque_f(w * 0.5f);   // block FMA contraction -> match XLA rounding
        float hh = opaque_f(h * 0.5f);
        float x1 = cx - hw, y1 = cy - hh, x2 = cx + hw, y2 = cy + hh;
        bx1[tid] = x1; by1[tid] = y1; bx2[tid] = x2; by2[tid] = y2;
        size_t o = (size_t)(b * MAXDET + tid);
        out[OFF_PB + o * 4 + 0] = x1;
        out[OFF_PB + o * 4 + 1] = y1;
        out[OFF_PB + o * 4 + 2] = x2;
        out[OFF_PB + o * 4 + 3] = y2;
        out[OFF_PS + o] = score;
        out[OFF_PL + o] = (float)lab;
    }
    if (tid < 10) keepw[tid] = (tid < 9) ? 0xFFFFFFFFu : 0xFFFu;  // 300 valid bits
    __syncthreads();
    // suppression matrix, parallel over pairs
    for (int p = tid; p < MAXDET * MAXDET; p += 512) {
        int i = p / MAXDET;
        int j = p - i * MAXDET;
        if (j > i) {
            float ai = (bx2[i] - bx1[i]) * (by2[i] - by1[i]);
            float aj = (bx2[j] - bx1[j]) * (by2[j] - by1[j]);
            float ltx = fmaxf(bx1[i], bx1[j]);
            float lty = fmaxf(by1[i], by1[j]);
            float rbx = fminf(bx2[i], bx2[j]);
            float rby = fminf(by2[i], by2[j]);
            float wx = fmaxf(rbx - ltx, 0.0f);
            float wy = fmaxf(rby - lty, 0.0f);
            float inter = wx * wy;
            float iou = inter / (ai + aj - inter + 1e-9f);  // left-to-right adds, no fma
            if (iou > 0.4f) atomicOr(&supp[i * 10 + (j >> 5)], 1u << (j & 31));
        }
    }
    __syncthreads();
    // sequential greedy scan: one wave, lane q owns keep word q, prefetch supp rows
    if (tid < 64) {
        int q = tid;
        unsigned kw = (q < 10) ? keepw[q] : 0u;
        unsigned nextrow = (q < 10) ? supp[q] : 0u;   // row 0
        for (int i = 0; i < MAXDET; ++i) {
            unsigned rowq = nextrow;
            if (q < 10 && i + 1 < MAXDET) nextrow = supp[(i + 1) * 10 + q];
            unsigned wown = __shfl(kw, i >> 5);        // uniform broadcast
            if ((wown >> (i & 31)) & 1u) kw &= ~rowq;  // rows only contain j>i bits
        }
        if (q < 10) keepw[q] = kw;
    }
    __syncthreads();
    if (tid < MAXDET)
        out[OFF_PK + (size_t)b * MAXDET + tid] =
            ((keepw[tid >> 5] >> (tid & 31)) & 1u) ? 1.0f : 0.0f;
}

// ---------------- Kernel D: targets ----------------
__global__ __launch_bounds__(64) void kD(const float* __restrict__ targets,
                                         const int* __restrict__ tlen,
                                         float* __restrict__ out) {
    int b = blockIdx.x, t = threadIdx.x;
    if (t >= TMAX) return;
    // int64-vs-int32 layout autodetect (lengths are in [1,49], never 0)
    bool is64 = (tlen[1] == 0) && (tlen[3] == 0) && (tlen[5] == 0);
    int len = is64 ? tlen[2 * b] : tlen[b];
    const float* r = targets + ((size_t)b * TMAX + t) * 6;
    float cx = r[0], cy = r[1], w = r[2], h = r[3], sc = r[4], lb = r[5];
    float hw = opaque_f(w * 0.5f);
    float hh = opaque_f(h * 0.5f);
    size_t o = (size_t)b * TMAX + t;
    out[OFF_TB + o * 4 + 0] = cx - hw;
    out[OFF_TB + o * 4 + 1] = cy - hh;
    out[OFF_TB + o * 4 + 2] = cx + hw;
    out[OFF_TB + o * 4 + 3] = cy + hh;
    out[OFF_TS + o] = sc;
    out[OFF_TL + o] = (float)(int)lb;
    out[OFF_TV + o] = (t < len) ? 1.0f : 0.0f;
}

extern "C" void kernel_launch(void* const* d_in, const int* in_sizes, int n_in,
                              void* d_out, int out_size, void* d_ws, size_t ws_size,
                              hipStream_t stream) {
    const float* logits  = (const float*)d_in[0];
    const float* targets = (const float*)d_in[1];
    const int*   tlen    = (const int*)d_in[2];
    float* out = (float*)d_out;
    char* ws = (char*)d_ws;
    int* cnt = (int*)ws;                                           // 16 x 64B
    unsigned long long* keys = (unsigned long long*)(ws + 1024);   // 16 x 8192 x u64
    unsigned long long* topk = (unsigned long long*)(ws + 1024 + (size_t)BATCH * CAP * 8);

    hipMemsetAsync(cnt, 0, 1024, stream);
    // 403200 anchors / 8 per wave = 50400 waves / 4 waves per block = 12600 blocks
    hipLaunchKernelGGL(kA, dim3(12600), dim3(256), 0, stream, logits, cnt, keys);
    hipLaunchKernelGGL(kB, dim3(BATCH), dim3(1024), 0, stream, cnt, keys, topk);
    hipLaunchKernelGGL(kC, dim3(BATCH), dim3(512), 0, stream, logits, topk, out);
    hipLaunchKernelGGL(kD, dim3(BATCH), dim3(64), 0, stream, targets, tlen, out);
}

// Round 4
// 161.122 us; speedup vs baseline: 2.8442x; 2.8442x over previous
//
#include <hip/hip_runtime.h>
#include <stdint.h>

#define BATCH   16
#define NANCH   25200
#define NCLS    80
#define REC     85
#define MAXDET  300
#define TMAX    50
#define NBUCKET 2048
#define FINCAP  1024

// output offsets (floats)
#define OFF_PB 0
#define OFF_PS 19200
#define OFF_PL 24000
#define OFF_PK 28800
#define OFF_TB 33600
#define OFF_TS 36800
#define OFF_TL 37600
#define OFF_TV 38400

__device__ __forceinline__ float opaque_f(float x) { asm volatile("" : "+v"(x)); return x; }

// ---------------- Kernel A: score -> dense conf_bits array ----------------
// Wave-per-8-anchors, coalesced reads, coalesced dense writes, ZERO atomics.
// confout[b*NANCH+n] = float bits of conf if conf>0.8 else 0. Index implicit.
__global__ __launch_bounds__(256) void kA(const float* __restrict__ logits,
                                          unsigned* __restrict__ confout) {
    const int wid  = (blockIdx.x * 256 + threadIdx.x) >> 6;   // global wave id
    const int lane = threadIdx.x & 63;
    const int a0   = wid * 8;                                 // 403200/8 waves exact
    const float* base = logits + (size_t)a0 * REC;
    float va[8], vb[8];
#pragma unroll
    for (int k = 0; k < 8; ++k) {
        const float* rec = base + k * REC;
        va[k] = rec[lane];                                    // fields 0..63
        vb[k] = (lane < 21) ? rec[64 + lane] : -1.0f;         // fields 64..84
    }
    unsigned keyreg = 0u;
#pragma unroll
    for (int k = 0; k < 8; ++k) {
        // classes are fields 5..84 -> va lanes 5..63, vb lanes 0..20
        float m = fmaxf((lane >= 5) ? va[k] : -1.0f, vb[k]);  // values in [0,1)
        m = fmaxf(m, __shfl_xor(m, 32));
        m = fmaxf(m, __shfl_xor(m, 16));
        m = fmaxf(m, __shfl_xor(m, 8));
        m = fmaxf(m, __shfl_xor(m, 4));
        m = fmaxf(m, __shfl_xor(m, 2));
        m = fmaxf(m, __shfl_xor(m, 1));
        float obj  = __shfl(va[k], 4);                        // field 4
        float conf = obj * m;                                 // exact: single multiply
        if (lane == k && conf > 0.8f) keyreg = __float_as_uint(conf);
    }
    if (lane < 8) confout[a0 + lane] = keyreg;                // 32B contiguous
}

// ---------------- Kernel B: scan + radix-select + bitonic top-300 ----------
__global__ __launch_bounds__(1024) void kB(const unsigned* __restrict__ confbits,
                                           unsigned long long* __restrict__ topkeys) {
    __shared__ unsigned hist[NBUCKET];
    __shared__ unsigned long long fin[FINCAP];
    __shared__ int sTb, sCnt;
    const int b = blockIdx.x;
    const int tid = threadIdx.x;
    const unsigned* cb = confbits + (size_t)b * NANCH;

    for (int i = tid; i < NBUCKET; i += 1024) hist[i] = 0u;
    if (tid == 0) sCnt = 0;
    __syncthreads();
    for (int i = tid; i < NANCH; i += 1024) {
        unsigned bits = cb[i];
        if (!bits) continue;                          // conf <= 0.8
        unsigned bk = (bits - 0x3F4CCCCDu) >> 11;     // linear in value (one binade)
        if (bk > NBUCKET - 1u) bk = NBUCKET - 1u;     // safety
        atomicAdd(&hist[bk], 1u);
    }
    __syncthreads();
    if (tid == 0) {
        int c = 0, tb = 0;
        for (int bk = NBUCKET - 1; bk >= 0; --bk) {
            c += (int)hist[bk];
            if (c >= MAXDET) { tb = bk; break; }
        }
        sTb = tb;
    }
    __syncthreads();
    int tb = sTb;
    for (int i = tid; i < NANCH; i += 1024) {
        unsigned bits = cb[i];
        if (!bits) continue;
        unsigned bk = (bits - 0x3F4CCCCDu) >> 11;
        if (bk > NBUCKET - 1u) bk = NBUCKET - 1u;
        if ((int)bk >= tb) {
            int p = atomicAdd(&sCnt, 1);
            if (p < FINCAP)
                fin[p] = ((unsigned long long)bits << 32) |
                         (unsigned)(0xFFFFFFFFu - (unsigned)i);  // ties: smaller idx first
        }
    }
    __syncthreads();
    int fc = sCnt; if (fc > FINCAP) fc = FINCAP;
    for (int i = tid; i < FINCAP; i += 1024) if (i >= fc) fin[i] = 0ull;
    // bitonic sort descending (keys unique -> deterministic)
    for (unsigned k = 2; k <= FINCAP; k <<= 1) {
        for (unsigned j = k >> 1; j > 0; j >>= 1) {
            __syncthreads();
            unsigned t = tid;
            unsigned ixj = t ^ j;
            if (ixj > t && t < FINCAP) {
                unsigned long long a = fin[t], c2 = fin[ixj];
                bool desc = ((t & k) == 0u);
                bool sw = desc ? (a < c2) : (a > c2);
                if (sw) { fin[t] = c2; fin[ixj] = a; }
            }
        }
    }
    __syncthreads();
    if (tid < MAXDET) topkeys[b * MAXDET + tid] = fin[tid];
}

// ---------------- Kernel C: gather + NMS + outputs ----------------
__global__ __launch_bounds__(512) void kC(const float* __restrict__ logits,
                                          const unsigned long long* __restrict__ topkeys,
                                          float* __restrict__ out) {
    __shared__ float bx1[MAXDET], by1[MAXDET], bx2[MAXDET], by2[MAXDET];
    __shared__ unsigned supp[MAXDET * 10];   // 300 rows x 320 bits
    __shared__ unsigned keepw[10];
    const int b = blockIdx.x;
    const int tid = threadIdx.x;
    for (int i = tid; i < MAXDET * 10; i += 512) supp[i] = 0u;
    if (tid < MAXDET) {
        unsigned long long key = topkeys[b * MAXDET + tid];
        float score = __uint_as_float((unsigned)(key >> 32));
        unsigned n = 0xFFFFFFFFu - (unsigned)(key & 0xFFFFFFFFull);
        if (n >= NANCH) n = 0;     // safety only; count >= 300 always
        const float* rec = logits + ((size_t)b * NANCH + n) * REC;
        float cx = rec[0], cy = rec[1], w = rec[2], h = rec[3];
        float bestv = rec[5]; int lab = 0;
        for (int c = 1; c < NCLS; ++c) {
            float v = rec[5 + c];
            if (v > bestv) { bestv = v; lab = c; }   // first-max, matches argmax
        }
        float hw = opaque_f(w * 0.5f);   // block FMA contraction -> match XLA rounding
        float hh = opaque_f(h * 0.5f);
        float x1 = cx - hw, y1 = cy - hh, x2 = cx + hw, y2 = cy + hh;
        bx1[tid] = x1; by1[tid] = y1; bx2[tid] = x2; by2[tid] = y2;
        size_t o = (size_t)(b * MAXDET + tid);
        out[OFF_PB + o * 4 + 0] = x1;
        out[OFF_PB + o * 4 + 1] = y1;
        out[OFF_PB + o * 4 + 2] = x2;
        out[OFF_PB + o * 4 + 3] = y2;
        out[OFF_PS + o] = score;
        out[OFF_PL + o] = (float)lab;
    }
    if (tid < 10) keepw[tid] = (tid < 9) ? 0xFFFFFFFFu : 0xFFFu;  // 300 valid bits
    __syncthreads();
    // suppression matrix, parallel over pairs
    for (int p = tid; p < MAXDET * MAXDET; p += 512) {
        int i = p / MAXDET;
        int j = p - i * MAXDET;
        if (j > i) {
            float ai = (bx2[i] - bx1[i]) * (by2[i] - by1[i]);
            float aj = (bx2[j] - bx1[j]) * (by2[j] - by1[j]);
            float ltx = fmaxf(bx1[i], bx1[j]);
            float lty = fmaxf(by1[i], by1[j]);
            float rbx = fminf(bx2[i], bx2[j]);
            float rby = fminf(by2[i], by2[j]);
            float wx = fmaxf(rbx - ltx, 0.0f);
            float wy = fmaxf(rby - lty, 0.0f);
            float inter = wx * wy;
            float iou = inter / (ai + aj - inter + 1e-9f);  // left-to-right adds, no fma
            if (iou > 0.4f) atomicOr(&supp[i * 10 + (j >> 5)], 1u << (j & 31));
        }
    }
    __syncthreads();
    // sequential greedy scan: one wave, lane q owns keep word q, prefetch supp rows
    if (tid < 64) {
        int q = tid;
        unsigned kw = (q < 10) ? keepw[q] : 0u;
        unsigned nextrow = (q < 10) ? supp[q] : 0u;   // row 0
        for (int i = 0; i < MAXDET; ++i) {
            unsigned rowq = nextrow;
            if (q < 10 && i + 1 < MAXDET) nextrow = supp[(i + 1) * 10 + q];
            unsigned wown = __shfl(kw, i >> 5);        // uniform broadcast
            if ((wown >> (i & 31)) & 1u) kw &= ~rowq;  // rows only contain j>i bits
        }
        if (q < 10) keepw[q] = kw;
    }
    __syncthreads();
    if (tid < MAXDET)
        out[OFF_PK + (size_t)b * MAXDET + tid] =
            ((keepw[tid >> 5] >> (tid & 31)) & 1u) ? 1.0f : 0.0f;
}

// ---------------- Kernel D: targets ----------------
__global__ __launch_bounds__(64) void kD(const float* __restrict__ targets,
                                         const int* __restrict__ tlen,
                                         float* __restrict__ out) {
    int b = blockIdx.x, t = threadIdx.x;
    if (t >= TMAX) return;
    // int64-vs-int32 layout autodetect (lengths are in [1,49], never 0)
    bool is64 = (tlen[1] == 0) && (tlen[3] == 0) && (tlen[5] == 0);
    int len = is64 ? tlen[2 * b] : tlen[b];
    const float* r = targets + ((size_t)b * TMAX + t) * 6;
    float cx = r[0], cy = r[1], w = r[2], h = r[3], sc = r[4], lb = r[5];
    float hw = opaque_f(w * 0.5f);
    float hh = opaque_f(h * 0.5f);
    size_t o = (size_t)b * TMAX + t;
    out[OFF_TB + o * 4 + 0] = cx - hw;
    out[OFF_TB + o * 4 + 1] = cy - hh;
    out[OFF_TB + o * 4 + 2] = cx + hw;
    out[OFF_TB + o * 4 + 3] = cy + hh;
    out[OFF_TS + o] = sc;
    out[OFF_TL + o] = (float)(int)lb;
    out[OFF_TV + o] = (t < len) ? 1.0f : 0.0f;
}

extern "C" void kernel_launch(void* const* d_in, const int* in_sizes, int n_in,
                              void* d_out, int out_size, void* d_ws, size_t ws_size,
                              hipStream_t stream) {
    const float* logits  = (const float*)d_in[0];
    const float* targets = (const float*)d_in[1];
    const int*   tlen    = (const int*)d_in[2];
    float* out = (float*)d_out;
    char* ws = (char*)d_ws;
    unsigned* confbits = (unsigned*)ws;                            // 403200 x u32 = 1.613 MB
    unsigned long long* topk =
        (unsigned long long*)(ws + (size_t)BATCH * NANCH * 4);     // 16 x 300 x u64

    // kA writes every confbits slot each call -> no init needed, no atomics anywhere global
    hipLaunchKernelGGL(kA, dim3(12600), dim3(256), 0, stream, logits, confbits);
    hipLaunchKernelGGL(kB, dim3(BATCH), dim3(1024), 0, stream, confbits, topk);
    hipLaunchKernelGGL(kC, dim3(BATCH), dim3(512), 0, stream, logits, topk, out);
    hipLaunchKernelGGL(kD, dim3(BATCH), dim3(64), 0, stream, targets, tlen, out);
}

// Round 5
// 104.956 us; speedup vs baseline: 4.3663x; 1.5351x over previous
//
#include <hip/hip_runtime.h>
#include <stdint.h>

#define BATCH   16
#define NANCH   25200
#define NCLS    80
#define REC     85
#define MAXDET  300
#define TMAX    50
#define NBUCKET 2048
#define FIN     512

// output offsets (floats)
#define OFF_PB 0
#define OFF_PS 19200
#define OFF_PL 24000
#define OFF_PK 28800
#define OFF_TB 33600
#define OFF_TS 36800
#define OFF_TL 37600
#define OFF_TV 38400

__device__ __forceinline__ float opaque_f(float x) { asm volatile("" : "+v"(x)); return x; }

// ---------------- Kernel A: score -> dense conf_bits array ----------------
// Per-thread anchor: 1 scalar + 20 float4 loads (wave consumes 64*340B
// contiguous across its burst -> every line fully used, L2 absorbs any L1
// thrash). Zero DS ops, zero atomics, dense coalesced store.
__global__ __launch_bounds__(256) void kA(const float* __restrict__ logits,
                                          unsigned* __restrict__ confout) {
    const int g = blockIdx.x * 256 + threadIdx.x;      // 1575*256 == 403200 exact
    const float* rec = logits + (size_t)g * REC;
    const float obj = rec[4];
    const float4* c4 = (const float4*)(rec + 5);       // 4B-aligned float4: ok on gfx950
    float m0 = -1.0f, m1 = -1.0f, m2 = -1.0f, m3 = -1.0f;
#pragma unroll
    for (int i = 0; i < 20; ++i) {
        float4 v = c4[i];
        m0 = fmaxf(m0, v.x); m1 = fmaxf(m1, v.y);
        m2 = fmaxf(m2, v.z); m3 = fmaxf(m3, v.w);
    }
    const float best = fmaxf(fmaxf(m0, m1), fmaxf(m2, m3));
    const float conf = obj * best;                     // exact: single multiply
    confout[g] = (conf > 0.8f) ? __float_as_uint(conf) : 0u;
}

// ------- Kernel BCD: select top-300 + sort + gather + NMS + targets -------
// One block per batch, 1024 threads.
__global__ __launch_bounds__(1024) void kBCD(const float* __restrict__ logits,
                                             const unsigned* __restrict__ confbits,
                                             const float* __restrict__ targets,
                                             const int* __restrict__ tlen,
                                             float* __restrict__ out) {
    __shared__ unsigned hist[NBUCKET];
    __shared__ unsigned long long fin[FIN];
    __shared__ unsigned long long srt[MAXDET];
    __shared__ float bx1[MAXDET], by1[MAXDET], bx2[MAXDET], by2[MAXDET];
    __shared__ unsigned supp[MAXDET * 10];   // 300 rows x 320 bits
    __shared__ unsigned keepw[10];
    __shared__ int sTb, sCnt;
    const int b = blockIdx.x;
    const int tid = threadIdx.x;

    // ---- targets (kD), folded into spare threads; no LDS, no deps ----
    if (tid >= 512 && tid < 512 + TMAX) {
        int t = tid - 512;
        bool is64 = (tlen[1] == 0) && (tlen[3] == 0) && (tlen[5] == 0);
        int len = is64 ? tlen[2 * b] : tlen[b];
        const float* r = targets + ((size_t)b * TMAX + t) * 6;
        float cx = r[0], cy = r[1], w = r[2], h = r[3], sc = r[4], lb = r[5];
        float hw = opaque_f(w * 0.5f);
        float hh = opaque_f(h * 0.5f);
        size_t o = (size_t)b * TMAX + t;
        out[OFF_TB + o * 4 + 0] = cx - hw;
        out[OFF_TB + o * 4 + 1] = cy - hh;
        out[OFF_TB + o * 4 + 2] = cx + hw;
        out[OFF_TB + o * 4 + 3] = cy + hh;
        out[OFF_TS + o] = sc;
        out[OFF_TL + o] = (float)(int)lb;
        out[OFF_TV + o] = (t < len) ? 1.0f : 0.0f;
    }

    // ---- init ----
    for (int i = tid; i < NBUCKET; i += 1024) hist[i] = 0u;
    for (int i = tid; i < MAXDET * 10; i += 1024) supp[i] = 0u;
    if (tid < MAXDET) srt[tid] = 0ull;
    if (tid < 10) keepw[tid] = (tid < 9) ? 0xFFFFFFFFu : 0xFFFu;  // 300 valid bits
    if (tid == 0) sCnt = 0;
    __syncthreads();

    // ---- histogram over this batch's conf bits ----
    const unsigned* cb = confbits + (size_t)b * NANCH;
    for (int i = tid; i < NANCH; i += 1024) {
        unsigned bits = cb[i];
        if (!bits) continue;                          // conf <= 0.8
        unsigned bk = (bits - 0x3F4CCCCDu) >> 11;     // linear in value (one binade)
        if (bk > NBUCKET - 1u) bk = NBUCKET - 1u;
        atomicAdd(&hist[bk], 1u);
    }
    __syncthreads();

    // ---- threshold bucket tb = max{bk : suffix_count(bk) >= 300}, wave 0 ----
    if (tid < 64) {
        const int l = tid;
        unsigned sup = 0u;                            // super-bucket sum (32 buckets)
        for (int j = 0; j < 32; ++j) sup += hist[l * 32 + j];
        unsigned ss = sup;                            // suffix scan over 64 supers
        for (int off = 1; off < 64; off <<= 1) {
            unsigned v = __shfl_down(ss, off);
            ss += (l + off < 64) ? v : 0u;
        }
        bool ge = ss >= MAXDET;                       // true for a prefix of lanes
        unsigned long long mask = __ballot(ge);
        int sstar = (mask == 0ull) ? 0 : (63 - __clzll(mask));
        unsigned tail = (sstar < 63) ? __shfl(ss, sstar + 1) : 0u;  // suffix from next super
        unsigned h = (l < 32) ? hist[sstar * 32 + l] : 0u;
        unsigned s2 = h;                              // suffix scan within super (32 lanes)
        for (int off = 1; off < 32; off <<= 1) {
            unsigned v = __shfl_down(s2, off);
            s2 += (l + off < 32) ? v : 0u;
        }
        bool ge2 = (l < 32) && (s2 + tail >= MAXDET);
        unsigned long long m2 = __ballot(ge2);
        int lstar = (m2 == 0ull) ? 0 : (63 - __clzll(m2));
        if (l == 0) sTb = sstar * 32 + lstar;
    }
    __syncthreads();

    // ---- compact candidates >= threshold bucket into fin[] (<= ~330) ----
    const int tb = sTb;
    for (int i = tid; i < NANCH; i += 1024) {
        unsigned bits = cb[i];
        if (!bits) continue;
        unsigned bk = (bits - 0x3F4CCCCDu) >> 11;
        if (bk > NBUCKET - 1u) bk = NBUCKET - 1u;
        if ((int)bk >= tb) {
            int p = atomicAdd(&sCnt, 1);
            if (p < FIN)
                fin[p] = ((unsigned long long)bits << 32) |
                         (unsigned)(0xFFFFFFFFu - (unsigned)i);  // ties: smaller idx first
        }
    }
    __syncthreads();
    const int fc = (sCnt < FIN) ? sCnt : FIN;

    // ---- rank-scatter sort: rank = #{keys > mine}; keys unique ----
    if (tid < fc) {
        unsigned long long k = fin[tid];
        int r = 0;
        for (int j = 0; j < fc; ++j) r += (fin[j] > k) ? 1 : 0;   // LDS broadcast reads
        if (r < MAXDET) srt[r] = k;
    }
    __syncthreads();

    // ---- gather records of top-300: boxes, labels, scores ----
    if (tid < MAXDET) {
        unsigned long long key = srt[tid];
        float score = __uint_as_float((unsigned)(key >> 32));
        unsigned n = 0xFFFFFFFFu - (unsigned)(key & 0xFFFFFFFFull);
        if (n >= NANCH) n = 0;     // safety only; count >= 300 always
        const float* rec = logits + ((size_t)b * NANCH + n) * REC;
        float cx = rec[0], cy = rec[1], w = rec[2], h = rec[3];
        float bestv = rec[5]; int lab = 0;
        for (int c = 1; c < NCLS; ++c) {
            float v = rec[5 + c];
            if (v > bestv) { bestv = v; lab = c; }   // first-max, matches argmax
        }
        float hw = opaque_f(w * 0.5f);   // block FMA contraction -> match XLA rounding
        float hh = opaque_f(h * 0.5f);
        float x1 = cx - hw, y1 = cy - hh, x2 = cx + hw, y2 = cy + hh;
        bx1[tid] = x1; by1[tid] = y1; bx2[tid] = x2; by2[tid] = y2;
        size_t o = (size_t)(b * MAXDET + tid);
        out[OFF_PB + o * 4 + 0] = x1;
        out[OFF_PB + o * 4 + 1] = y1;
        out[OFF_PB + o * 4 + 2] = x2;
        out[OFF_PB + o * 4 + 3] = y2;
        out[OFF_PS + o] = score;
        out[OFF_PL + o] = (float)lab;
    }
    __syncthreads();

    // ---- suppression matrix, parallel over pairs ----
    for (int p = tid; p < MAXDET * MAXDET; p += 1024) {
        int i = p / MAXDET;
        int j = p - i * MAXDET;
        if (j > i) {
            float ai = (bx2[i] - bx1[i]) * (by2[i] - by1[i]);
            float aj = (bx2[j] - bx1[j]) * (by2[j] - by1[j]);
            float ltx = fmaxf(bx1[i], bx1[j]);
            float lty = fmaxf(by1[i], by1[j]);
            float rbx = fminf(bx2[i], bx2[j]);
            float rby = fminf(by2[i], by2[j]);
            float wx = fmaxf(rbx - ltx, 0.0f);
            float wy = fmaxf(rby - lty, 0.0f);
            float inter = wx * wy;
            float iou = inter / (ai + aj - inter + 1e-9f);  // left-to-right, no fma
            if (iou > 0.4f) atomicOr(&supp[i * 10 + (j >> 5)], 1u << (j & 31));
        }
    }
    __syncthreads();

    // ---- sequential greedy scan: one wave, lane q owns keep word q ----
    if (tid < 64) {
        int q = tid;
        unsigned kw = (q < 10) ? keepw[q] : 0u;
        unsigned nextrow = (q < 10) ? supp[q] : 0u;   // row 0
        for (int i = 0; i < MAXDET; ++i) {
            unsigned rowq = nextrow;
            if (q < 10 && i + 1 < MAXDET) nextrow = supp[(i + 1) * 10 + q];
            unsigned wown = __shfl(kw, i >> 5);        // uniform broadcast
            if ((wown >> (i & 31)) & 1u) kw &= ~rowq;  // rows only contain j>i bits
        }
        if (q < 10) keepw[q] = kw;
    }
    __syncthreads();
    if (tid < MAXDET)
        out[OFF_PK + (size_t)b * MAXDET + tid] =
            ((keepw[tid >> 5] >> (tid & 31)) & 1u) ? 1.0f : 0.0f;
}

extern "C" void kernel_launch(void* const* d_in, const int* in_sizes, int n_in,
                              void* d_out, int out_size, void* d_ws, size_t ws_size,
                              hipStream_t stream) {
    const float* logits  = (const float*)d_in[0];
    const float* targets = (const float*)d_in[1];
    const int*   tlen    = (const int*)d_in[2];
    float* out = (float*)d_out;
    unsigned* confbits = (unsigned*)d_ws;              // 403200 x u32 = 1.613 MB

    hipLaunchKernelGGL(kA, dim3(1575), dim3(256), 0, stream, logits, confbits);
    hipLaunchKernelGGL(kBCD, dim3(BATCH), dim3(1024), 0, stream,
                       logits, confbits, targets, tlen, out);
}

// Round 6
// 97.770 us; speedup vs baseline: 4.6872x; 1.0735x over previous
//
#include <hip/hip_runtime.h>
#include <stdint.h>

#define BATCH   16
#define NANCH   25200
#define NCLS    80
#define REC     85
#define MAXDET  300
#define TMAX    50
#define NBUCKET 2048
#define FIN     512

// output offsets (floats)
#define OFF_PB 0
#define OFF_PS 19200
#define OFF_PL 24000
#define OFF_PK 28800
#define OFF_TB 33600
#define OFF_TS 36800
#define OFF_TL 37600
#define OFF_TV 38400

__device__ __forceinline__ float opaque_f(float x) { asm volatile("" : "+v"(x)); return x; }

// ---------------- Kernel A: score -> dense conf_bits array ----------------
// 4 lanes per anchor: lane j loads the 5 float4s covering classes
// [5+20j, 24+20j] (80 classes exact), all 4 lanes load obj (same line,
// broadcast). Per-instruction wave window = 16 records = 5.4KB, fully
// consumed in a 6-instruction burst -> minimal L1 live footprint.
// Reduce: 19 lane-local fmax + shfl_xor(1) + shfl_xor(2). Zero atomics.
__global__ __launch_bounds__(256) void kA(const float* __restrict__ logits,
                                          unsigned* __restrict__ confout) {
    const int wid  = (blockIdx.x * 256 + threadIdx.x) >> 6;   // global wave id
    const int lane = threadIdx.x & 63;
    const int t    = lane >> 2;                               // anchor slot 0..15
    const int j    = lane & 3;                                // quarter 0..3
    const int a    = wid * 16 + t;                            // 25200 waves exact
    const float* rec = logits + (size_t)a * REC;
    const float obj = rec[4];                                 // same line x4: broadcast
    const float* cls = rec + 5 + j * 20;
    float4 v0 = *(const float4*)(cls + 0);
    float4 v1 = *(const float4*)(cls + 4);
    float4 v2 = *(const float4*)(cls + 8);
    float4 v3 = *(const float4*)(cls + 12);
    float4 v4 = *(const float4*)(cls + 16);
    float m0 = fmaxf(fmaxf(v0.x, v0.y), fmaxf(v0.z, v0.w));
    float m1 = fmaxf(fmaxf(v1.x, v1.y), fmaxf(v1.z, v1.w));
    float m2 = fmaxf(fmaxf(v2.x, v2.y), fmaxf(v2.z, v2.w));
    float m3 = fmaxf(fmaxf(v3.x, v3.y), fmaxf(v3.z, v3.w));
    float m4 = fmaxf(fmaxf(v4.x, v4.y), fmaxf(v4.z, v4.w));
    float m  = fmaxf(fmaxf(fmaxf(m0, m1), fmaxf(m2, m3)), m4);   // 20-local max
    m = fmaxf(m, __shfl_xor(m, 1));                            // within 4-group
    m = fmaxf(m, __shfl_xor(m, 2));
    const float conf = obj * m;                                // exact: single multiply
    if (j == 0)
        confout[a] = (conf > 0.8f) ? __float_as_uint(conf) : 0u;  // 64B/wave contiguous
}

// ------- Kernel BCD: select top-300 + sort + gather + NMS + targets -------
// One block per batch, 1024 threads.
__global__ __launch_bounds__(1024) void kBCD(const float* __restrict__ logits,
                                             const unsigned* __restrict__ confbits,
                                             const float* __restrict__ targets,
                                             const int* __restrict__ tlen,
                                             float* __restrict__ out) {
    __shared__ unsigned hist[NBUCKET];
    __shared__ unsigned long long fin[FIN];
    __shared__ unsigned long long srt[MAXDET];
    __shared__ float bx1[MAXDET], by1[MAXDET], bx2[MAXDET], by2[MAXDET];
    __shared__ unsigned supp[MAXDET * 10];   // 300 rows x 320 bits
    __shared__ unsigned keepw[10];
    __shared__ int sTb, sCnt;
    const int b = blockIdx.x;
    const int tid = threadIdx.x;

    // ---- targets (kD), folded into spare threads; no LDS, no deps ----
    if (tid >= 512 && tid < 512 + TMAX) {
        int t = tid - 512;
        bool is64 = (tlen[1] == 0) && (tlen[3] == 0) && (tlen[5] == 0);
        int len = is64 ? tlen[2 * b] : tlen[b];
        const float* r = targets + ((size_t)b * TMAX + t) * 6;
        float cx = r[0], cy = r[1], w = r[2], h = r[3], sc = r[4], lb = r[5];
        float hw = opaque_f(w * 0.5f);
        float hh = opaque_f(h * 0.5f);
        size_t o = (size_t)b * TMAX + t;
        out[OFF_TB + o * 4 + 0] = cx - hw;
        out[OFF_TB + o * 4 + 1] = cy - hh;
        out[OFF_TB + o * 4 + 2] = cx + hw;
        out[OFF_TB + o * 4 + 3] = cy + hh;
        out[OFF_TS + o] = sc;
        out[OFF_TL + o] = (float)(int)lb;
        out[OFF_TV + o] = (t < len) ? 1.0f : 0.0f;
    }

    // ---- init ----
    for (int i = tid; i < NBUCKET; i += 1024) hist[i] = 0u;
    for (int i = tid; i < MAXDET * 10; i += 1024) supp[i] = 0u;
    if (tid < MAXDET) srt[tid] = 0ull;
    if (tid < 10) keepw[tid] = (tid < 9) ? 0xFFFFFFFFu : 0xFFFu;  // 300 valid bits
    if (tid == 0) sCnt = 0;
    __syncthreads();

    // ---- histogram over this batch's conf bits ----
    const unsigned* cb = confbits + (size_t)b * NANCH;
    for (int i = tid; i < NANCH; i += 1024) {
        unsigned bits = cb[i];
        if (!bits) continue;                          // conf <= 0.8
        unsigned bk = (bits - 0x3F4CCCCDu) >> 11;     // linear in value (one binade)
        if (bk > NBUCKET - 1u) bk = NBUCKET - 1u;
        atomicAdd(&hist[bk], 1u);
    }
    __syncthreads();

    // ---- threshold bucket tb = max{bk : suffix_count(bk) >= 300}, wave 0 ----
    if (tid < 64) {
        const int l = tid;
        unsigned sup = 0u;                            // super-bucket sum (32 buckets)
        for (int j = 0; j < 32; ++j) sup += hist[l * 32 + j];
        unsigned ss = sup;                            // suffix scan over 64 supers
        for (int off = 1; off < 64; off <<= 1) {
            unsigned v = __shfl_down(ss, off);
            ss += (l + off < 64) ? v : 0u;
        }
        bool ge = ss >= MAXDET;                       // true for a prefix of lanes
        unsigned long long mask = __ballot(ge);
        int sstar = (mask == 0ull) ? 0 : (63 - __clzll(mask));
        unsigned tail = (sstar < 63) ? __shfl(ss, sstar + 1) : 0u;  // suffix from next super
        unsigned h = (l < 32) ? hist[sstar * 32 + l] : 0u;
        unsigned s2 = h;                              // suffix scan within super (32 lanes)
        for (int off = 1; off < 32; off <<= 1) {
            unsigned v = __shfl_down(s2, off);
            s2 += (l + off < 32) ? v : 0u;
        }
        bool ge2 = (l < 32) && (s2 + tail >= MAXDET);
        unsigned long long m2 = __ballot(ge2);
        int lstar = (m2 == 0ull) ? 0 : (63 - __clzll(m2));
        if (l == 0) sTb = sstar * 32 + lstar;
    }
    __syncthreads();

    // ---- compact candidates >= threshold bucket into fin[] (<= ~330) ----
    const int tb = sTb;
    for (int i = tid; i < NANCH; i += 1024) {
        unsigned bits = cb[i];
        if (!bits) continue;
        unsigned bk = (bits - 0x3F4CCCCDu) >> 11;
        if (bk > NBUCKET - 1u) bk = NBUCKET - 1u;
        if ((int)bk >= tb) {
            int p = atomicAdd(&sCnt, 1);
            if (p < FIN)
                fin[p] = ((unsigned long long)bits << 32) |
                         (unsigned)(0xFFFFFFFFu - (unsigned)i);  // ties: smaller idx first
        }
    }
    __syncthreads();
    const int fc = (sCnt < FIN) ? sCnt : FIN;

    // ---- rank-scatter sort: rank = #{keys > mine}; keys unique ----
    if (tid < fc) {
        unsigned long long k = fin[tid];
        int r = 0;
        for (int j = 0; j < fc; ++j) r += (fin[j] > k) ? 1 : 0;   // LDS broadcast reads
        if (r < MAXDET) srt[r] = k;
    }
    __syncthreads();

    // ---- gather records of top-300: boxes, labels, scores ----
    if (tid < MAXDET) {
        unsigned long long key = srt[tid];
        float score = __uint_as_float((unsigned)(key >> 32));
        unsigned n = 0xFFFFFFFFu - (unsigned)(key & 0xFFFFFFFFull);
        if (n >= NANCH) n = 0;     // safety only; count >= 300 always
        const float* rec = logits + ((size_t)b * NANCH + n) * REC;
        float cx = rec[0], cy = rec[1], w = rec[2], h = rec[3];
        float bestv = rec[5]; int lab = 0;
        for (int c = 1; c < NCLS; ++c) {
            float v = rec[5 + c];
            if (v > bestv) { bestv = v; lab = c; }   // first-max, matches argmax
        }
        float hw = opaque_f(w * 0.5f);   // block FMA contraction -> match XLA rounding
        float hh = opaque_f(h * 0.5f);
        float x1 = cx - hw, y1 = cy - hh, x2 = cx + hw, y2 = cy + hh;
        bx1[tid] = x1; by1[tid] = y1; bx2[tid] = x2; by2[tid] = y2;
        size_t o = (size_t)(b * MAXDET + tid);
        out[OFF_PB + o * 4 + 0] = x1;
        out[OFF_PB + o * 4 + 1] = y1;
        out[OFF_PB + o * 4 + 2] = x2;
        out[OFF_PB + o * 4 + 3] = y2;
        out[OFF_PS + o] = score;
        out[OFF_PL + o] = (float)lab;
    }
    __syncthreads();

    // ---- suppression matrix, parallel over pairs ----
    for (int p = tid; p < MAXDET * MAXDET; p += 1024) {
        int i = p / MAXDET;
        int j = p - i * MAXDET;
        if (j > i) {
            float ai = (bx2[i] - bx1[i]) * (by2[i] - by1[i]);
            float aj = (bx2[j] - bx1[j]) * (by2[j] - by1[j]);
            float ltx = fmaxf(bx1[i], bx1[j]);
            float lty = fmaxf(by1[i], by1[j]);
            float rbx = fminf(bx2[i], bx2[j]);
            float rby = fminf(by2[i], by2[j]);
            float wx = fmaxf(rbx - ltx, 0.0f);
            float wy = fmaxf(rby - lty, 0.0f);
            float inter = wx * wy;
            float iou = inter / (ai + aj - inter + 1e-9f);  // left-to-right, no fma
            if (iou > 0.4f) atomicOr(&supp[i * 10 + (j >> 5)], 1u << (j & 31));
        }
    }
    __syncthreads();

    // ---- sequential greedy scan: one wave, lane q owns keep word q ----
    if (tid < 64) {
        int q = tid;
        unsigned kw = (q < 10) ? keepw[q] : 0u;
        unsigned nextrow = (q < 10) ? supp[q] : 0u;   // row 0
        for (int i = 0; i < MAXDET; ++i) {
            unsigned rowq = nextrow;
            if (q < 10 && i + 1 < MAXDET) nextrow = supp[(i + 1) * 10 + q];
            unsigned wown = __shfl(kw, i >> 5);        // uniform broadcast
            if ((wown >> (i & 31)) & 1u) kw &= ~rowq;  // rows only contain j>i bits
        }
        if (q < 10) keepw[q] = kw;
    }
    __syncthreads();
    if (tid < MAXDET)
        out[OFF_PK + (size_t)b * MAXDET + tid] =
            ((keepw[tid >> 5] >> (tid & 31)) & 1u) ? 1.0f : 0.0f;
}

extern "C" void kernel_launch(void* const* d_in, const int* in_sizes, int n_in,
                              void* d_out, int out_size, void* d_ws, size_t ws_size,
                              hipStream_t stream) {
    const float* logits  = (const float*)d_in[0];
    const float* targets = (const float*)d_in[1];
    const int*   tlen    = (const int*)d_in[2];
    float* out = (float*)d_out;
    unsigned* confbits = (unsigned*)d_ws;              // 403200 x u32 = 1.613 MB

    // 403200 anchors / 16 per wave = 25200 waves / 4 per block = 6300 blocks
    hipLaunchKernelGGL(kA, dim3(6300), dim3(256), 0, stream, logits, confbits);
    hipLaunchKernelGGL(kBCD, dim3(BATCH), dim3(1024), 0, stream,
                       logits, confbits, targets, tlen, out);
}